// Round 9
// baseline (351.713 us; speedup 1.0000x reference)
//
#include <hip/hip_runtime.h>
#include <cstdint>
#include <cstddef>

// Problem constants
#define NN    50000
#define EE    800000
#define ET    850000   /* EE + NN self-loops */
#define SLOPE 0.2f
#define MT64  782      /* (NN+63)/64 gemm row-blocks */
#define SCB   831      /* (ET+1023)/1024 scatter blocks (4 edges/thread) */
#define CAP   96       /* per-node edge bucket capacity (max in-deg ~45) */

typedef unsigned short ushortT;
typedef __attribute__((ext_vector_type(8))) short short8;
typedef __attribute__((ext_vector_type(4))) float floatx4;

__device__ __forceinline__ float lrelu(float x){ return x > 0.f ? x : SLOPE * x; }
__device__ __forceinline__ float eluf(float x){ return x > 0.f ? x : __expf(x) - 1.f; }
__device__ __forceinline__ ushortT f2b(float f){ unsigned u = __float_as_uint(f); u += 0x7fff + ((u >> 16) & 1); return (ushortT)(u >> 16); }
__device__ __forceinline__ float   b2f(ushortT b){ return __uint_as_float(((unsigned)b) << 16); }

__device__ __forceinline__ void edge_sd(const int* __restrict__ srcA, const int* __restrict__ dstA,
                                        int e, int& s, int& d)
{
    if (e < EE) { s = srcA[e]; d = dstA[e]; }
    else        { s = e - EE;  d = s; }
}

// ---------------------------------------------------------------------------
// GEMM body: C[M, NT*16](bf16) = A[M,256] @ BT[NT*16,256]^T
// + fused attention-logit epilogue. 64 rows/block, 4 waves (16 rows/wave).
// Small tile => acc[NT]=64 VGPR, 25.6KB LDS => ~4 blocks/CU (vs 2 at 128-row).
// ---------------------------------------------------------------------------
template<bool A_F32, int NT, int HEADS>
__device__ __forceinline__ void gemm_body(const void* __restrict__ Aptr,
                                          const ushortT* __restrict__ BT,
                                          const float* __restrict__ attS,
                                          const float* __restrict__ attD,
                                          ushortT* __restrict__ C,
                                          float* __restrict__ asrc,
                                          float* __restrict__ adst,
                                          int M, int bId,
                                          ushortT* As, ushortT* Bs)
{
    constexpr int NCOL = NT * 16;
    const int tid  = threadIdx.x;
    const int wave = tid >> 6;
    const int lane = tid & 63;
    const int m16  = lane & 15;
    const int quad = lane >> 4;
    const int row0 = bId * 64;
    const int arow = tid >> 2;           // 0..63
    const int acol = (tid & 3) << 3;     // 0,8,16,24 (bf16 units)
    const long arowG = min(row0 + arow, M - 1);

    floatx4 acc[NT];
    #pragma unroll
    for (int j = 0; j < NT; ++j) acc[j] = (floatx4){0.f, 0.f, 0.f, 0.f};

    for (int k0 = 0; k0 < 256; k0 += 32) {
        ushortT a16[8];
        if (A_F32) {
            const float* A = (const float*)Aptr;
            float4 f0 = *(const float4*)(A + arowG * 256 + k0 + acol);
            float4 f1 = *(const float4*)(A + arowG * 256 + k0 + acol + 4);
            a16[0]=f2b(f0.x); a16[1]=f2b(f0.y); a16[2]=f2b(f0.z); a16[3]=f2b(f0.w);
            a16[4]=f2b(f1.x); a16[5]=f2b(f1.y); a16[6]=f2b(f1.z); a16[7]=f2b(f1.w);
        } else {
            *(uint4*)a16 = *(const uint4*)((const ushortT*)Aptr + arowG * 256 + k0 + acol);
        }
        uint4 bst[(NT == 16) ? 4 : 1];
        if (NT == 16) {
            const ushortT* bp = BT + (size_t)tid * 256 + k0;   // 1 row/thread, 32 bf16
            #pragma unroll
            for (int q = 0; q < 4; ++q) bst[q] = *(const uint4*)(bp + q * 8);
        } else {
            int brow = tid >> 2, bcol = (tid & 3) << 3;        // 64 rows, 4 thr/row
            bst[0] = *(const uint4*)(BT + (size_t)brow * 256 + k0 + bcol);
        }

        __syncthreads();
        *(uint4*)(&As[arow * 40 + acol]) = *(uint4*)a16;
        if (NT == 16) {
            #pragma unroll
            for (int q = 0; q < 4; ++q) *(uint4*)(&Bs[tid * 40 + q * 8]) = bst[q];
        } else {
            int brow = tid >> 2, bcol = (tid & 3) << 3;
            *(uint4*)(&Bs[brow * 40 + bcol]) = bst[0];
        }
        __syncthreads();

        short8 af = *(const short8*)(&As[(wave * 16 + m16) * 40 + quad * 8]);
        #pragma unroll
        for (int j = 0; j < NT; ++j) {
            short8 bf = *(const short8*)(&Bs[(j * 16 + m16) * 40 + quad * 8]);
            acc[j] = __builtin_amdgcn_mfma_f32_16x16x32_bf16(af, bf, acc[j], 0, 0, 0);
        }
    }

    float attSv[NT], attDv[NT];
    #pragma unroll
    for (int j = 0; j < NT; ++j) {
        attSv[j] = attS[j * 16 + m16];
        attDv[j] = attD[j * 16 + m16];
    }

    #pragma unroll
    for (int r = 0; r < 4; ++r) {
        int row = row0 + wave * 16 + quad * 4 + r;
        bool ok = row < M;
        if (ok) {
            #pragma unroll
            for (int j = 0; j < NT; ++j)
                C[(size_t)row * NCOL + j * 16 + m16] = f2b(acc[j][r]);
        }
        float ds[HEADS], dd[HEADS];
        #pragma unroll
        for (int h = 0; h < HEADS; ++h) {
            float s = 0.f, d2 = 0.f;
            #pragma unroll
            for (int jj = 0; jj < 4; ++jj) {
                int j = h * 4 + jj;
                s  += acc[j][r] * attSv[j];
                d2 += acc[j][r] * attDv[j];
            }
            #pragma unroll
            for (int off = 1; off < 16; off <<= 1) {
                s  += __shfl_xor(s, off);
                d2 += __shfl_xor(d2, off);
            }
            ds[h] = s; dd[h] = d2;
        }
        if (ok && m16 == 0) {
            if (HEADS == 4) {
                *(float4*)(asrc + (size_t)row * 4) = make_float4(ds[0], ds[1], ds[2], ds[3]);
                *(float4*)(adst + (size_t)row * 4) = make_float4(dd[0], dd[1], dd[2], dd[3]);
            } else {
                asrc[row] = ds[0];
                adst[row] = dd[0];
            }
        }
    }
}

// ---------------------------------------------------------------------------
// Fused prep: blocks [0,256) cast weights; [256,..) DIRECT bucket-scatter:
// rank = atomicAdd(cnt+d,1); esorted[d*CAP+rank] = s. The rank from the
// histogram atomic IS the position -> no prefix scan, no second atomic pass.
// All parts low-VGPR/no-LDS -> full occupancy.
// ---------------------------------------------------------------------------
__global__ __launch_bounds__(256) void prep_k(const float* __restrict__ W1, const float* __restrict__ W2,
                                              ushortT* __restrict__ W1T, ushortT* __restrict__ W2T,
                                              const int* __restrict__ srcA, const int* __restrict__ dstA,
                                              int* __restrict__ cnt, int* __restrict__ esorted)
{
    int t = threadIdx.x;
    int b = blockIdx.x;
    if (b < 256) {
        W1T[t * 256 + b] = f2b(W1[b * 256 + t]);
        if (t < 64) W2T[t * 256 + b] = f2b(W2[b * 64 + t]);
    } else {
        int e0 = (b - 256) * 1024 + t;
        #pragma unroll
        for (int k = 0; k < 4; ++k) {
            int e = e0 + k * 256;
            if (e < ET) {
                int s, d; edge_sd(srcA, dstA, e, s, d);
                int r = atomicAdd(cnt + d, 1);
                if (r < CAP) esorted[d * CAP + r] = s;   // clamp: P(deg>CAP) ~ 1e-40
            }
        }
    }
}

// Layer-1 GEMM standalone (f32 A inline-cast; x read exactly once)
__global__ __launch_bounds__(256, 4) void gemm1_k(const float* __restrict__ x,
                                                  const ushortT* __restrict__ W1T,
                                                  const float* __restrict__ attS,
                                                  const float* __restrict__ attD,
                                                  ushortT* __restrict__ h1b,
                                                  float* __restrict__ asrc,
                                                  float* __restrict__ adst)
{
    __shared__ ushortT As[64 * 40];
    __shared__ ushortT Bs[256 * 40];
    gemm_body<true, 16, 4>(x, W1T, attS, attD, h1b, asrc, adst, NN, blockIdx.x, As, Bs);
}

// Layer-2 GEMM standalone
__global__ __launch_bounds__(256, 4) void gemm2_k(const ushortT* __restrict__ a2b,
                                                  const ushortT* __restrict__ W2T,
                                                  const float* __restrict__ attS,
                                                  const float* __restrict__ attD,
                                                  ushortT* __restrict__ t2b,
                                                  float* __restrict__ asrc,
                                                  float* __restrict__ adst)
{
    __shared__ ushortT As[64 * 40];
    __shared__ ushortT Bs[64 * 40];
    gemm_body<false, 4, 1>(a2b, W2T, attS, attD, t2b, asrc, adst, NN, blockIdx.x, As, Bs);
}

// ---------------------------------------------------------------------------
// agg1: chunked pass. Lane=edge computes p (4 heads) once into wave-local LDS;
// all lanes gather h1b rows weighted by LDS-broadcast p. Phase B unroll 8.
// Segment = esorted[n*CAP .. n*CAP+deg). No max-subtraction (logits O(7)).
// ---------------------------------------------------------------------------
__global__ __launch_bounds__(256) void agg1_k(const int* __restrict__ esorted,
                                              const int* __restrict__ cnt,
                                              const ushortT* __restrict__ h1b,
                                              const float* __restrict__ asrc,
                                              const float* __restrict__ adst,
                                              const float* __restrict__ b1,
                                              ushortT* __restrict__ a2b)
{
    __shared__ float pbuf[4][64][4];
    __shared__ int   sbuf[4][64];
    int w = threadIdx.x >> 6;
    int lane = threadIdx.x & 63;
    int n = blockIdx.x * 4 + w;
    if (n >= NN) return;
    int start = n * CAP;
    int deg = min(cnt[n], CAP);
    float4 adv = *(const float4*)(adst + (size_t)n * 4);
    int h = lane >> 4;
    int c4 = lane * 4;

    float4 ssv = make_float4(0.f, 0.f, 0.f, 0.f);
    float4 ac0 = make_float4(0.f,0.f,0.f,0.f);
    float4 ac1 = make_float4(0.f,0.f,0.f,0.f);
    float4 ac2 = make_float4(0.f,0.f,0.f,0.f);
    float4 ac3 = make_float4(0.f,0.f,0.f,0.f);

    for (int base = 0; base < deg; base += 64) {
        int cl = min(64, deg - base);
        int i = base + lane;
        if (i < deg) {
            int s = esorted[start + i];
            float4 a = *(const float4*)(asrc + (size_t)s * 4);
            float4 pv;
            pv.x = __expf(lrelu(a.x + adv.x));
            pv.y = __expf(lrelu(a.y + adv.y));
            pv.z = __expf(lrelu(a.z + adv.z));
            pv.w = __expf(lrelu(a.w + adv.w));
            ssv.x += pv.x; ssv.y += pv.y; ssv.z += pv.z; ssv.w += pv.w;
            *(float4*)(&pbuf[w][lane][0]) = pv;
            sbuf[w][lane] = s;
        }
        __builtin_amdgcn_wave_barrier();   // intra-wave LDS write->read ordering
        int j = 0;
        for (; j + 7 < cl; j += 8) {
            float4 hv[8]; float pp[8];
            #pragma unroll
            for (int q = 0; q < 8; ++q) {
                int sq = sbuf[w][j + q];
                pp[q] = pbuf[w][j + q][h];
                ushort4 hq = *(const ushort4*)(h1b + (size_t)sq * 256 + c4);
                hv[q] = make_float4(b2f(hq.x), b2f(hq.y), b2f(hq.z), b2f(hq.w));
            }
            #pragma unroll
            for (int q = 0; q < 8; ++q) {
                float4* ac = (q & 3) == 0 ? &ac0 : (q & 3) == 1 ? &ac1 : (q & 3) == 2 ? &ac2 : &ac3;
                ac->x += hv[q].x * pp[q]; ac->y += hv[q].y * pp[q];
                ac->z += hv[q].z * pp[q]; ac->w += hv[q].w * pp[q];
            }
        }
        for (; j < cl; ++j) {
            int s0 = sbuf[w][j];
            float p0 = pbuf[w][j][h];
            ushort4 h0 = *(const ushort4*)(h1b + (size_t)s0 * 256 + c4);
            ac0.x += b2f(h0.x) * p0; ac0.y += b2f(h0.y) * p0; ac0.z += b2f(h0.z) * p0; ac0.w += b2f(h0.w) * p0;
        }
        __builtin_amdgcn_wave_barrier();   // reads done before next chunk's writes
    }

    #pragma unroll
    for (int off = 1; off < 64; off <<= 1) {
        ssv.x += __shfl_xor(ssv.x, off); ssv.y += __shfl_xor(ssv.y, off);
        ssv.z += __shfl_xor(ssv.z, off); ssv.w += __shfl_xor(ssv.w, off);
    }
    float ssh = (h < 2) ? (h == 0 ? ssv.x : ssv.y) : (h == 2 ? ssv.z : ssv.w);
    float rdh = 1.f / ssh;

    float4 bv = *(const float4*)(b1 + c4);
    ushort4 o;
    o.x = f2b(eluf((ac0.x + ac1.x + ac2.x + ac3.x) * rdh + bv.x));
    o.y = f2b(eluf((ac0.y + ac1.y + ac2.y + ac3.y) * rdh + bv.y));
    o.z = f2b(eluf((ac0.z + ac1.z + ac2.z + ac3.z) * rdh + bv.z));
    o.w = f2b(eluf((ac0.w + ac1.w + ac2.w + ac3.w) * rdh + bv.w));
    *(ushort4*)(a2b + (size_t)n * 256 + c4) = o;
}

// ---------------------------------------------------------------------------
// agg2: same chunked-LDS structure, 1 head + bias + log_softmax. Unroll 8.
// ---------------------------------------------------------------------------
__global__ __launch_bounds__(256) void agg2_k(const int* __restrict__ esorted,
                                              const int* __restrict__ cnt,
                                              const ushortT* __restrict__ t2b,
                                              const float* __restrict__ asrc,
                                              const float* __restrict__ adst,
                                              const float* __restrict__ b2,
                                              float* __restrict__ out)
{
    __shared__ float pbuf[4][64];
    __shared__ int   sbuf[4][64];
    int w = threadIdx.x >> 6;
    int lane = threadIdx.x & 63;
    int n = blockIdx.x * 4 + w;
    if (n >= NN) return;
    int start = n * CAP;
    int deg = min(cnt[n], CAP);
    float adv = adst[n];

    float ss = 0.f;
    float a0 = 0.f, a1 = 0.f, a2 = 0.f, a3 = 0.f;

    for (int base = 0; base < deg; base += 64) {
        int cl = min(64, deg - base);
        int i = base + lane;
        if (i < deg) {
            int s = esorted[start + i];
            float p = __expf(lrelu(asrc[s] + adv));
            ss += p;
            pbuf[w][lane] = p;
            sbuf[w][lane] = s;
        }
        __builtin_amdgcn_wave_barrier();
        int j = 0;
        for (; j + 7 < cl; j += 8) {
            float tv[8]; float pp[8];
            #pragma unroll
            for (int q = 0; q < 8; ++q) {
                int sq = sbuf[w][j + q];
                pp[q] = pbuf[w][j + q];
                tv[q] = b2f(t2b[(size_t)sq * 64 + lane]);
            }
            #pragma unroll
            for (int q = 0; q < 8; ++q) {
                float* ac = (q & 3) == 0 ? &a0 : (q & 3) == 1 ? &a1 : (q & 3) == 2 ? &a2 : &a3;
                *ac += tv[q] * pp[q];
            }
        }
        for (; j < cl; ++j) {
            a0 += b2f(t2b[(size_t)sbuf[w][j] * 64 + lane]) * pbuf[w][j];
        }
        __builtin_amdgcn_wave_barrier();
    }

    #pragma unroll
    for (int off = 1; off < 64; off <<= 1) ss += __shfl_xor(ss, off);
    float v = (a0 + a1 + a2 + a3) / ss + b2[lane];

    float m2 = v;
    #pragma unroll
    for (int off = 32; off; off >>= 1) m2 = fmaxf(m2, __shfl_xor(m2, off));
    float ex = __expf(v - m2);
    float sm = ex;
    #pragma unroll
    for (int off = 32; off; off >>= 1) sm += __shfl_xor(sm, off);
    out[(size_t)n * 64 + lane] = v - m2 - __logf(sm);
}

// ---------------------------------------------------------------------------
extern "C" void kernel_launch(void* const* d_in, const int* in_sizes, int n_in,
                              void* d_out, int out_size, void* d_ws, size_t ws_size,
                              hipStream_t stream)
{
    const float* x   = (const float*)d_in[0];
    const int*   adj = (const int*)  d_in[1];
    const float* W1  = (const float*)d_in[2];
    const float* as1 = (const float*)d_in[3];
    const float* ad1 = (const float*)d_in[4];
    const float* b1  = (const float*)d_in[5];
    const float* W2  = (const float*)d_in[6];
    const float* as2 = (const float*)d_in[7];
    const float* ad2 = (const float*)d_in[8];
    const float* b2  = (const float*)d_in[9];
    float* out = (float*)d_out;

    const size_t szH1b = (size_t)NN * 256 * 2;   // 25.6 MB
    const size_t szT2b = (size_t)NN * 64 * 2;    // 6.4 MB
    const size_t szA4  = (size_t)NN * 4 * 4;     // 0.8 MB
    const size_t szA1  = (size_t)NN * 4;         // 0.2 MB
    const size_t szE   = (size_t)NN * CAP * 4;   // 19.2 MB

    char* p = (char*)d_ws;
    ushortT* h1b  = (ushortT*)p; p += szH1b;
    ushortT* a2b  = (ushortT*)p; p += szH1b;
    ushortT* t2b  = (ushortT*)p; p += szT2b;
    ushortT* W1T  = (ushortT*)p; p += 256 * 256 * 2;
    ushortT* W2T  = (ushortT*)p; p += 64 * 256 * 2;
    float* asrc1  = (float*)p; p += szA4;
    float* adst1  = (float*)p; p += szA4;
    float* asrc2  = (float*)p; p += szA1;
    float* adst2  = (float*)p; p += szA1;
    int* esorted  = (int*)p; p += szE;
    int* cnt      = (int*)p; p += szA1;

    hipMemsetAsync(cnt, 0, szA1, stream);

    const int nwb = (NN + 3) / 4;       // 12500

    // castW (blocks 0..255) + direct bucket-scatter (blocks 256..)
    prep_k<<<256 + SCB, 256, 0, stream>>>(W1, W2, W1T, W2T, adj, adj + EE, cnt, esorted);

    // Layer 1
    gemm1_k<<<MT64, 256, 0, stream>>>(x, W1T, as1, ad1, h1b, asrc1, adst1);
    agg1_k<<<nwb, 256, 0, stream>>>(esorted, cnt, h1b, asrc1, adst1, b1, a2b);

    // Layer 2
    gemm2_k<<<MT64, 256, 0, stream>>>(a2b, W2T, as2, ad2, t2b, asrc2, adst2);
    agg2_k<<<nwb, 256, 0, stream>>>(esorted, cnt, t2b, asrc2, adst2, b2, out);
}